// Round 9
// baseline (544.101 us; speedup 1.0000x reference)
//
#include <hip/hip_runtime.h>
#include <cstdint>
#include <cstddef>

// LIF recurrent SNN, sinabs ThresholdSubtract.
// Round-9: BREAK THE PER-CU BANDWIDTH WALL.
//   R2/R7/R8 all converged at 176us == 131MB / (32 CUs x ~10B/cy/CU) -- the
//   per-CU vmem delivery limit, not latency (R8's producer waves + deep ring
//   changed nothing). Fix: split each batch row over 8 blocks (128 neurons
//   each) = 256 blocks / 256 CUs -> 8x the delivery bandwidth.
//   Sequential coupling handled by SPECULATIVE row consensus:
//     * per chunk (8 steps), each block posts arrival|spike bits via atomicOr
//       into flags[row][epoch&1][chunk]; consensus is checked lazily for
//       chunk i-2 (slack hides the flag round trip; flag load issued early).
//     * on consensus-spike (rare, ~6.6/row): all 8 blocks publish their
//       chunk-start state/rec snapshots; the row leader (slice 0) replays the
//       chunk exactly (all 1024 neurons, rank-1 w updates, spike records),
//       publishes corrected state/rec, clears the next epoch's flag slot,
//       releases done; everyone resumes from the corrected state.
//   Output zeroing interleaved into the scan (4KB/iter/block, covers the
//   block's own t-range); spikes for a t-range are written at the END by the
//   block that zeroed it (same-wave program order -> no cross-XCD dirty-line
//   ordering hazard). No separate zero blocks, no scatter kernel.
#define ROWS_   32
#define SLICES_ 8
#define T_      1000
#define N_      1024
#define NCH_    125          // chunks of 8 steps
#define TPB_    64           // one wave per block; 2 neurons per lane

typedef float v2f __attribute__((ext_vector_type(2)));
typedef float v4f __attribute__((ext_vector_type(4)));

__device__ __forceinline__ unsigned atload(unsigned* p) {
  return __hip_atomic_load(p, __ATOMIC_RELAXED, __HIP_MEMORY_SCOPE_AGENT);
}

__device__ __forceinline__ v4f act4(v4f s) {
  v4f a;
  a.x = (s.x > 0.f) ? floorf(s.x) : 0.f;
  a.y = (s.y > 0.f) ? floorf(s.y) : 0.f;
  a.z = (s.z > 0.f) ? floorf(s.z) : 0.f;
  a.w = (s.w > 0.f) ? floorf(s.w) : 0.f;
  return a;
}
__device__ __forceinline__ unsigned msk4(v4f a, int sh) {
  return ((a.x != 0.f ? 1u : 0u) | (a.y != 0.f ? 2u : 0u) |
          (a.z != 0.f ? 4u : 0u) | (a.w != 0.f ? 8u : 0u)) << sh;
}

// zero the inter-block control region of ws (flags/ready/done/recn)
__global__ void init_ctrl(unsigned* p, int nwords) {
  for (int i = threadIdx.x; i < nwords; i += blockDim.x) p[i] = 0u;
}

__global__ __launch_bounds__(TPB_, 1)
void lif_split(const float* __restrict__ x, const float* __restrict__ w,
               const float* __restrict__ brec_g, float* __restrict__ out,
               unsigned* flags, unsigned* ready, unsigned* done,
               unsigned* recn, unsigned long long* recl,
               float* sbufA, float* rbufA, float* sbufB, float* rbufB)
{
  const int g    = blockIdx.x;
  const int r    = g & 31;        // row: row's 8 slices land on one XCD (g%... 32s+r -> XCD r%8)
  const int s    = g >> 5;        // slice 0..7 (slice 0 = row leader)
  const int lane = threadIdx.x;   // 0..63; owns neurons s*128 + 2*lane (+1)

  const float* xrow   = x + (size_t)r * (T_ * N_) + s * 128 + lane * 2;
  float*       outrow = out + (size_t)r * (T_ * N_);
  v4f*         zbase  = (v4f*)(outrow + (size_t)s * 125 * N_); // my t-range
  const v2f    brecv  = *(const v2f*)(brec_g + s * 128 + lane * 2);

  unsigned* flg0 = flags + (r * 2 + 0) * 128;
  unsigned* flg1 = flags + (r * 2 + 1) * 128;

  __shared__ float lacts[N_];     // leader replay act broadcast

  v2f state = (v2f)(0.f), recc = (v2f)(0.f);   // chunk-0 rec = 0 (NOT brec)
  v2f sA = state, sB = state, sC = state;      // starts of chunks i-2,i-1,i
  v2f rA = recc,  rB = recc,  rC = recc;
  int jdone = -1, seq = 0;
  const v4f z4 = (v4f)(0.f);

#pragma unroll 1
  for (int i = 0; i < NCH_ + 2; ++i) {
    // early-issue the consensus flag load for chunk i-2
    const int j = i - 2;
    const bool needc = (j > jdone) && (j >= 0);
    unsigned* slot = (seq & 1) ? flg1 : flg0;
    unsigned f = 0;
    if (needc) f = atload(slot + j);

    v2f newstate = state, newrec = recc;
    if (i < NCH_) {
      // interleaved zeroing: 4KB of my out t-range per iteration
      v4f* zp = zbase + (size_t)i * 256;
      __builtin_nontemporal_store(z4, zp +   0 + lane);
      __builtin_nontemporal_store(z4, zp +  64 + lane);
      __builtin_nontemporal_store(z4, zp + 128 + lane);
      __builtin_nontemporal_store(z4, zp + 192 + lane);

      // speculative no-spike pass on chunk i (spike iff pre-update s >= 1)
      const float* xp = xrow + (size_t)i * (8 * N_);
      v2f x0 = *(const v2f*)(xp + 0 * N_), x1 = *(const v2f*)(xp + 1 * N_);
      v2f x2 = *(const v2f*)(xp + 2 * N_), x3 = *(const v2f*)(xp + 3 * N_);
      v2f x4 = *(const v2f*)(xp + 4 * N_), x5 = *(const v2f*)(xp + 5 * N_);
      v2f x6 = *(const v2f*)(xp + 6 * N_), x7 = *(const v2f*)(xp + 7 * N_);
      v2f st = state, rr = recc, cm = state;
#define SSTEP(xk)                                                            \
      do {                                                                   \
        cm.x = fmaxf(cm.x, st.x); cm.y = fmaxf(cm.y, st.y);                  \
        v2f _t = (xk) + rr;                                                  \
        st = st * 0.9f + 0.1f * _t;                                          \
        rr = brecv;                                                          \
      } while (0)
      SSTEP(x0); SSTEP(x1); SSTEP(x2); SSTEP(x3);
      SSTEP(x4); SSTEP(x5); SSTEP(x6); SSTEP(x7);
#undef SSTEP
      int any = (fmaxf(cm.x, cm.y) >= 1.0f);
      unsigned long long bal = __ballot(any);
      if (lane == 0)
        atomicOr(slot + i, (1u << s) | (bal ? (256u << s) : 0u));
      newstate = st; newrec = brecv;
    }

    if (needc) {
      while ((f & 255u) != 255u) {            // all 8 slices posted?
        __builtin_amdgcn_s_sleep(2);
        f = atload(slot + j);
      }
      if (f >> 8) {
        // ---------------- rollback & exact repair of chunk j ----------------
        const int cs = j;
        const int sb = r * 1024 + s * 128 + lane * 2;
        sbufA[sb + 0] = sA.x; sbufA[sb + 1] = sA.y;   // start(cs) state
        rbufA[sb + 0] = rA.x; rbufA[sb + 1] = rA.y;   // start(cs) rec
        __threadfence();
        if (lane == 0) atomicAdd(&ready[r], 1u);

        if (s == 0) {
          // -------- leader: exact replay of chunk cs over all 1024 neurons
          const unsigned tgt = 8u * (unsigned)(seq + 1);
          while (atload(&ready[r]) < tgt) __builtin_amdgcn_s_sleep(2);
          __threadfence();
          const int nl = lane * 16;             // my 16 neurons
          v4f s0 = *(v4f*)(sbufA + r * 1024 + nl + 0);
          v4f s1 = *(v4f*)(sbufA + r * 1024 + nl + 4);
          v4f s2 = *(v4f*)(sbufA + r * 1024 + nl + 8);
          v4f s3 = *(v4f*)(sbufA + r * 1024 + nl + 12);
          v4f r0 = *(v4f*)(rbufA + r * 1024 + nl + 0);
          v4f r1 = *(v4f*)(rbufA + r * 1024 + nl + 4);
          v4f r2 = *(v4f*)(rbufA + r * 1024 + nl + 8);
          v4f r3 = *(v4f*)(rbufA + r * 1024 + nl + 12);
          const v4f bb0 = *(const v4f*)(brec_g + nl + 0);
          const v4f bb1 = *(const v4f*)(brec_g + nl + 4);
          const v4f bb2 = *(const v4f*)(brec_g + nl + 8);
          const v4f bb3 = *(const v4f*)(brec_g + nl + 12);
          unsigned rn = atload(&recn[r]);
          const float* xc = x + (size_t)r * (T_ * N_) + (size_t)cs * 8 * N_ + nl;
#pragma unroll 1
          for (int k = 0; k < 8; ++k) {
            v4f xa = *(const v4f*)(xc + k * N_ + 0);
            v4f xb = *(const v4f*)(xc + k * N_ + 4);
            v4f xcv = *(const v4f*)(xc + k * N_ + 8);
            v4f xd = *(const v4f*)(xc + k * N_ + 12);
            v4f t0 = xa + r0, t1 = xb + r1, t2 = xcv + r2, t3 = xd + r3;
            v4f a0 = act4(s0), a1 = act4(s1), a2 = act4(s2), a3 = act4(s3);
            unsigned m16 = msk4(a0, 0) | msk4(a1, 4) | msk4(a2, 8) | msk4(a3, 12);
            if (m16) {
              *(v4f*)(lacts + nl + 0)  = a0; *(v4f*)(lacts + nl + 4)  = a1;
              *(v4f*)(lacts + nl + 8)  = a2; *(v4f*)(lacts + nl + 12) = a3;
            }
            unsigned long long spk = __ballot(m16 != 0);
            s0 = (s0 - a0) * 0.9f + 0.1f * t0;
            s1 = (s1 - a1) * 0.9f + 0.1f * t1;
            s2 = (s2 - a2) * 0.9f + 0.1f * t2;
            s3 = (s3 - a3) * 0.9f + 0.1f * t3;
            r0 = bb0; r1 = bb1; r2 = bb2; r3 = bb3;
            while (spk) {                       // rank-1 per spiking neuron
              int L = __builtin_ctzll(spk); spk &= spk - 1;
              unsigned m = (unsigned)__shfl((int)m16, L);
              while (m) {
                int bp = __builtin_ctz(m); m &= m - 1;
                int jj = (L << 4) + bp;
                float a = lacts[jj];
                const float* wc = w + jj;
                r0.x += a * wc[(size_t)(nl + 0) * N_];
                r0.y += a * wc[(size_t)(nl + 1) * N_];
                r0.z += a * wc[(size_t)(nl + 2) * N_];
                r0.w += a * wc[(size_t)(nl + 3) * N_];
                r1.x += a * wc[(size_t)(nl + 4) * N_];
                r1.y += a * wc[(size_t)(nl + 5) * N_];
                r1.z += a * wc[(size_t)(nl + 6) * N_];
                r1.w += a * wc[(size_t)(nl + 7) * N_];
                r2.x += a * wc[(size_t)(nl + 8) * N_];
                r2.y += a * wc[(size_t)(nl + 9) * N_];
                r2.z += a * wc[(size_t)(nl + 10) * N_];
                r2.w += a * wc[(size_t)(nl + 11) * N_];
                r3.x += a * wc[(size_t)(nl + 12) * N_];
                r3.y += a * wc[(size_t)(nl + 13) * N_];
                r3.z += a * wc[(size_t)(nl + 14) * N_];
                r3.w += a * wc[(size_t)(nl + 15) * N_];
                if (lane == 0) {                // record spike (t*N + n, val)
                  unsigned off = (unsigned)((cs * 8 + k) * N_ + jj);
                  recl[r * 256 + (rn & 255u)] =
                      ((unsigned long long)off << 32) |
                      (unsigned long long)__float_as_uint(a);
                  rn++;
                }
              }
            }
          }
          *(v4f*)(sbufB + r * 1024 + nl + 0)  = s0;
          *(v4f*)(sbufB + r * 1024 + nl + 4)  = s1;
          *(v4f*)(sbufB + r * 1024 + nl + 8)  = s2;
          *(v4f*)(sbufB + r * 1024 + nl + 12) = s3;
          *(v4f*)(rbufB + r * 1024 + nl + 0)  = r0;
          *(v4f*)(rbufB + r * 1024 + nl + 4)  = r1;
          *(v4f*)(rbufB + r * 1024 + nl + 8)  = r2;
          *(v4f*)(rbufB + r * 1024 + nl + 12) = r3;
          if (lane == 0)
            __hip_atomic_store(&recn[r], rn, __ATOMIC_RELAXED,
                               __HIP_MEMORY_SCOPE_AGENT);
          // clear the NEXT epoch's flag slot for chunks cs+1..124
          unsigned* ns = ((seq + 1) & 1) ? flg1 : flg0;
          for (int c = cs + 1 + lane; c < NCH_; c += 64) ns[c] = 0u;
          __threadfence();
          if (lane == 0)
            __hip_atomic_store(&done[r], (unsigned)(seq + 1),
                               __ATOMIC_RELEASE, __HIP_MEMORY_SCOPE_AGENT);
        }

        while (atload(&done[r]) < (unsigned)(seq + 1))
          __builtin_amdgcn_s_sleep(2);
        __threadfence();
        state.x = sbufB[sb + 0]; state.y = sbufB[sb + 1];
        recc.x  = rbufB[sb + 0]; recc.y  = rbufB[sb + 1];
        sA = sB = sC = state; rA = rB = rC = recc;
        seq += 1;
        jdone = cs;
        i = cs;                 // ++i -> resume at cs+1
        continue;               // skip commit shift
      }
      jdone = j;
    }

    // commit: rotate snapshots, advance state
    sA = sB; sB = sC; sC = newstate;
    rA = rB; rB = rC; rC = newrec;
    state = newstate; recc = newrec;
  }

  // flush spikes belonging to my t-range (after all my zero stores: same-wave
  // program order guarantees zero-then-spike for any shared address)
  unsigned n = atload(&recn[r]);
  __threadfence();
  if (n > 256u) n = 256u;
  for (unsigned e = lane; e < n; e += 64) {
    unsigned long long rc = recl[r * 256 + e];
    unsigned off = (unsigned)(rc >> 32);
    unsigned t = off >> 10;
    if (t / 125u == (unsigned)s)
      outrow[off] = __uint_as_float((unsigned)rc);
  }
}

extern "C" void kernel_launch(void* const* d_in, const int* in_sizes, int n_in,
                              void* d_out, int out_size, void* d_ws, size_t ws_size,
                              hipStream_t stream) {
  const float* x  = (const float*)d_in[0]; // [B,T,N] input_current
  const float* w  = (const float*)d_in[1]; // [N,N] w_rec (row-major [out,in])
  const float* br = (const float*)d_in[2]; // [N] b_rec
  float* out = (float*)d_out;              // [B,T,N] spikes

  // ws layout (bytes):
  //   flags u32[32][2][128]        @ 0       (32768)
  //   ready u32[32]                @ 32768   (128)
  //   done  u32[32]                @ 32896   (128)
  //   recn  u32[32]                @ 33024   (128)
  //   recl  u64[32][256]           @ 33152   (65536)
  //   sbufA f32[32][1024]          @ 98688   (131072)
  //   rbufA f32[32][1024]          @ 229760  (131072)
  //   sbufB f32[32][1024]          @ 360832  (131072)
  //   rbufB f32[32][1024]          @ 491904  (131072)  -> total 622976
  char* base = (char*)d_ws;
  unsigned* flags = (unsigned*)(base);
  unsigned* ready = (unsigned*)(base + 32768);
  unsigned* done  = (unsigned*)(base + 32896);
  unsigned* recn  = (unsigned*)(base + 33024);
  unsigned long long* recl = (unsigned long long*)(base + 33152);
  float* sbufA = (float*)(base + 98688);
  float* rbufA = (float*)(base + 229760);
  float* sbufB = (float*)(base + 360832);
  float* rbufB = (float*)(base + 491904);

  init_ctrl<<<1, 256, 0, stream>>>(flags, 33152 / 4);
  lif_split<<<ROWS_ * SLICES_, TPB_, 0, stream>>>(
      x, w, br, out, flags, ready, done, recn, recl,
      sbufA, rbufA, sbufB, rbufB);
}

// Round 10
// 537.068 us; speedup vs baseline: 1.0131x; 1.0131x over previous
//
#include <hip/hip_runtime.h>
#include <cstdint>
#include <cstddef>

// LIF recurrent SNN, sinabs ThresholdSubtract.
// Round-10: R9's 8-blocks-per-row split (breaks the ~10B/cy/CU delivery wall
//   measured invariant across R2/R7/R8) with the consensus cost removed:
//   * post via RELAXED AGENT ATOMIC STORES to per-slice words (8 independent
//     u32/chunk) -- R9's atomicOr was an RMW: 8 slices serialized on one line
//     every chunk (~2.4kcy/chunk). Stores are fire-and-forget.
//   * checker reads the 8 words with 4 pipelined u64 relaxed loads issued at
//     iteration top, consumed after compute -> latency hidden.
//   * slack W=4 chunks (5 register snapshots) instead of 2 -> inter-block
//     jitter absorbed, completeness check almost always already satisfied.
//   Repair path (validated bit-exact in R9: passed with real spikes): on
//   consensus-spike all slices publish chunk-start state/rec; row leader
//   replays the chunk exactly for all 1024 neurons (rank-1 w updates, spike
//   records), publishes corrected state, clears next-epoch flags, releases.
//   Zeroing interleaved (each block zeroes its own t-range; spikes for that
//   range flushed by the same block at the end -> same-wave ordering, no
//   cross-XCD dirty-line hazard).
#define ROWS_   32
#define SLICES_ 8
#define T_      1000
#define N_      1024
#define NCH_    125          // chunks of 8 steps
#define TPB_    64           // one wave per block; 2 neurons per lane
#define W_      4            // confirmation slack (chunks)

typedef float v2f __attribute__((ext_vector_type(2)));
typedef float v4f __attribute__((ext_vector_type(4)));

__device__ __forceinline__ unsigned atload(unsigned* p) {
  return __hip_atomic_load(p, __ATOMIC_RELAXED, __HIP_MEMORY_SCOPE_AGENT);
}
__device__ __forceinline__ unsigned long long atload64(const unsigned long long* p) {
  return __hip_atomic_load(p, __ATOMIC_RELAXED, __HIP_MEMORY_SCOPE_AGENT);
}
__device__ __forceinline__ void atstore(unsigned* p, unsigned v) {
  __hip_atomic_store(p, v, __ATOMIC_RELAXED, __HIP_MEMORY_SCOPE_AGENT);
}

__device__ __forceinline__ v4f act4(v4f s) {
  v4f a;
  a.x = (s.x > 0.f) ? floorf(s.x) : 0.f;
  a.y = (s.y > 0.f) ? floorf(s.y) : 0.f;
  a.z = (s.z > 0.f) ? floorf(s.z) : 0.f;
  a.w = (s.w > 0.f) ? floorf(s.w) : 0.f;
  return a;
}
__device__ __forceinline__ unsigned msk4(v4f a, int sh) {
  return ((a.x != 0.f ? 1u : 0u) | (a.y != 0.f ? 2u : 0u) |
          (a.z != 0.f ? 4u : 0u) | (a.w != 0.f ? 8u : 0u)) << sh;
}

// zero the inter-block control region of ws (flags/ready/done/recn)
__global__ void init_ctrl(unsigned* p, int nwords) {
  int i = blockIdx.x * blockDim.x + threadIdx.x;
  int stride = gridDim.x * blockDim.x;
  for (; i < nwords; i += stride) p[i] = 0u;
}

__global__ __launch_bounds__(TPB_, 1)
void lif_split(const float* __restrict__ x, const float* __restrict__ w,
               const float* __restrict__ brec_g, float* __restrict__ out,
               unsigned* flags, unsigned* ready, unsigned* done,
               unsigned* recn, unsigned long long* recl,
               float* sbufA, float* rbufA, float* sbufB, float* rbufB)
{
  const int g    = blockIdx.x;
  const int r    = g & 31;        // row; the row's 8 slices share one XCD (g%8==r%8)
  const int s    = g >> 5;        // slice 0..7 (slice 0 = row leader)
  const int lane = threadIdx.x;   // 0..63; owns neurons s*128 + 2*lane (+1)

  const float* xrow   = x + (size_t)r * (T_ * N_) + s * 128 + lane * 2;
  float*       outrow = out + (size_t)r * (T_ * N_);
  v4f*         zbase  = (v4f*)(outrow + (size_t)s * 125 * N_); // my t-range
  const v2f    brecv  = *(const v2f*)(brec_g + s * 128 + lane * 2);

  __shared__ float lacts[N_];     // leader replay act broadcast

  v2f state = (v2f)(0.f), recc = (v2f)(0.f);   // chunk-0 rec = 0 (NOT brec)
  // snapshot ring: sA=start(i-4) .. sD=start(i-1); current state = start(i)
  v2f sA = state, sB = state, sC = state, sD = state;
  v2f rA = recc,  rB = recc,  rC = recc,  rD = recc;
  int jdone = -1, seq = 0;
  const v4f z4 = (v4f)(0.f);

#pragma unroll 1
  for (int i = 0; i < NCH_ + W_; ++i) {
    // flags base for current epoch parity: [row][parity][chunk][slice]
    unsigned* slot = flags + (((r << 1) | (seq & 1)) << 10); // 128*8 words
    const int j = i - W_;
    const bool needc = (j > jdone) && (j >= 0);
    // early-issue the 8 consensus words for chunk j (4 pipelined u64 loads)
    unsigned long long f0 = 0, f1 = 0, f2 = 0, f3 = 0;
    const unsigned long long* fp =
        (const unsigned long long*)(slot + (j << 3));
    if (needc) { f0 = atload64(fp); f1 = atload64(fp + 1);
                 f2 = atload64(fp + 2); f3 = atload64(fp + 3); }

    v2f newstate = state, newrec = recc;
    if (i < NCH_) {
      // interleaved zeroing: 4KB of my out t-range per iteration
      v4f* zp = zbase + (size_t)i * 256;
      __builtin_nontemporal_store(z4, zp +   0 + lane);
      __builtin_nontemporal_store(z4, zp +  64 + lane);
      __builtin_nontemporal_store(z4, zp + 128 + lane);
      __builtin_nontemporal_store(z4, zp + 192 + lane);

      // speculative no-spike pass on chunk i (spike iff pre-update s >= 1)
      const float* xp = xrow + (size_t)i * (8 * N_);
      v2f x0 = *(const v2f*)(xp + 0 * N_), x1 = *(const v2f*)(xp + 1 * N_);
      v2f x2 = *(const v2f*)(xp + 2 * N_), x3 = *(const v2f*)(xp + 3 * N_);
      v2f x4 = *(const v2f*)(xp + 4 * N_), x5 = *(const v2f*)(xp + 5 * N_);
      v2f x6 = *(const v2f*)(xp + 6 * N_), x7 = *(const v2f*)(xp + 7 * N_);
      v2f st = state, rr = recc, cm = state;
#define SSTEP(xk)                                                            \
      do {                                                                   \
        cm.x = fmaxf(cm.x, st.x); cm.y = fmaxf(cm.y, st.y);                  \
        v2f _t = (xk) + rr;                                                  \
        st = st * 0.9f + 0.1f * _t;                                          \
        rr = brecv;                                                          \
      } while (0)
      SSTEP(x0); SSTEP(x1); SSTEP(x2); SSTEP(x3);
      SSTEP(x4); SSTEP(x5); SSTEP(x6); SSTEP(x7);
#undef SSTEP
      int any = (fmaxf(cm.x, cm.y) >= 1.0f);
      unsigned long long bal = __ballot(any);
      if (lane == 0)
        atstore(slot + (i << 3) + s, bal ? 3u : 1u);  // plain atomic store, no RMW
      newstate = st; newrec = brecv;
    }

    if (needc) {
      // completeness: all 8 words have bit0 (issued pre-compute -> usually done)
      for (;;) {
        unsigned long long pp = f0 & f1 & f2 & f3;
        if ((pp & 1ull) && (pp & (1ull << 32))) break;
        __builtin_amdgcn_s_sleep(4);
        f0 = atload64(fp); f1 = atload64(fp + 1);
        f2 = atload64(fp + 2); f3 = atload64(fp + 3);
      }
      unsigned long long oo = f0 | f1 | f2 | f3;
      if (oo & 0x0000000200000002ull) {
        // ---------------- rollback & exact repair of chunk j ----------------
        const int cs = j;
        const int sb = r * 1024 + s * 128 + lane * 2;
        sbufA[sb + 0] = sA.x; sbufA[sb + 1] = sA.y;   // start(cs) state
        rbufA[sb + 0] = rA.x; rbufA[sb + 1] = rA.y;   // start(cs) rec
        __threadfence();
        if (lane == 0) atomicAdd(&ready[r], 1u);

        if (s == 0) {
          // -------- leader: exact replay of chunk cs over all 1024 neurons
          const unsigned tgt = 8u * (unsigned)(seq + 1);
          while (atload(&ready[r]) < tgt) __builtin_amdgcn_s_sleep(2);
          __threadfence();
          const int nl = lane * 16;             // my 16 neurons
          v4f s0 = *(v4f*)(sbufA + r * 1024 + nl + 0);
          v4f s1 = *(v4f*)(sbufA + r * 1024 + nl + 4);
          v4f s2 = *(v4f*)(sbufA + r * 1024 + nl + 8);
          v4f s3 = *(v4f*)(sbufA + r * 1024 + nl + 12);
          v4f r0 = *(v4f*)(rbufA + r * 1024 + nl + 0);
          v4f r1 = *(v4f*)(rbufA + r * 1024 + nl + 4);
          v4f r2 = *(v4f*)(rbufA + r * 1024 + nl + 8);
          v4f r3 = *(v4f*)(rbufA + r * 1024 + nl + 12);
          const v4f bb0 = *(const v4f*)(brec_g + nl + 0);
          const v4f bb1 = *(const v4f*)(brec_g + nl + 4);
          const v4f bb2 = *(const v4f*)(brec_g + nl + 8);
          const v4f bb3 = *(const v4f*)(brec_g + nl + 12);
          unsigned rn = atload(&recn[r]);
          const float* xc = x + (size_t)r * (T_ * N_) + (size_t)cs * 8 * N_ + nl;
#pragma unroll 1
          for (int k = 0; k < 8; ++k) {
            v4f xa = *(const v4f*)(xc + k * N_ + 0);
            v4f xb = *(const v4f*)(xc + k * N_ + 4);
            v4f xcv = *(const v4f*)(xc + k * N_ + 8);
            v4f xd = *(const v4f*)(xc + k * N_ + 12);
            v4f t0 = xa + r0, t1 = xb + r1, t2 = xcv + r2, t3 = xd + r3;
            v4f a0 = act4(s0), a1 = act4(s1), a2 = act4(s2), a3 = act4(s3);
            unsigned m16 = msk4(a0, 0) | msk4(a1, 4) | msk4(a2, 8) | msk4(a3, 12);
            if (m16) {
              *(v4f*)(lacts + nl + 0)  = a0; *(v4f*)(lacts + nl + 4)  = a1;
              *(v4f*)(lacts + nl + 8)  = a2; *(v4f*)(lacts + nl + 12) = a3;
            }
            unsigned long long spk = __ballot(m16 != 0);
            s0 = (s0 - a0) * 0.9f + 0.1f * t0;
            s1 = (s1 - a1) * 0.9f + 0.1f * t1;
            s2 = (s2 - a2) * 0.9f + 0.1f * t2;
            s3 = (s3 - a3) * 0.9f + 0.1f * t3;
            r0 = bb0; r1 = bb1; r2 = bb2; r3 = bb3;
            while (spk) {                       // rank-1 per spiking neuron
              int L = __builtin_ctzll(spk); spk &= spk - 1;
              unsigned m = (unsigned)__shfl((int)m16, L);
              while (m) {
                int bp = __builtin_ctz(m); m &= m - 1;
                int jj = (L << 4) + bp;
                float a = lacts[jj];
                const float* wc = w + jj;
                r0.x += a * wc[(size_t)(nl + 0) * N_];
                r0.y += a * wc[(size_t)(nl + 1) * N_];
                r0.z += a * wc[(size_t)(nl + 2) * N_];
                r0.w += a * wc[(size_t)(nl + 3) * N_];
                r1.x += a * wc[(size_t)(nl + 4) * N_];
                r1.y += a * wc[(size_t)(nl + 5) * N_];
                r1.z += a * wc[(size_t)(nl + 6) * N_];
                r1.w += a * wc[(size_t)(nl + 7) * N_];
                r2.x += a * wc[(size_t)(nl + 8) * N_];
                r2.y += a * wc[(size_t)(nl + 9) * N_];
                r2.z += a * wc[(size_t)(nl + 10) * N_];
                r2.w += a * wc[(size_t)(nl + 11) * N_];
                r3.x += a * wc[(size_t)(nl + 12) * N_];
                r3.y += a * wc[(size_t)(nl + 13) * N_];
                r3.z += a * wc[(size_t)(nl + 14) * N_];
                r3.w += a * wc[(size_t)(nl + 15) * N_];
                if (lane == 0) {                // record spike (t*N + n, val)
                  unsigned off = (unsigned)((cs * 8 + k) * N_ + jj);
                  recl[r * 256 + (rn & 255u)] =
                      ((unsigned long long)off << 32) |
                      (unsigned long long)__float_as_uint(a);
                  rn++;
                }
              }
            }
          }
          *(v4f*)(sbufB + r * 1024 + nl + 0)  = s0;
          *(v4f*)(sbufB + r * 1024 + nl + 4)  = s1;
          *(v4f*)(sbufB + r * 1024 + nl + 8)  = s2;
          *(v4f*)(sbufB + r * 1024 + nl + 12) = s3;
          *(v4f*)(rbufB + r * 1024 + nl + 0)  = r0;
          *(v4f*)(rbufB + r * 1024 + nl + 4)  = r1;
          *(v4f*)(rbufB + r * 1024 + nl + 8)  = r2;
          *(v4f*)(rbufB + r * 1024 + nl + 12) = r3;
          if (lane == 0)
            __hip_atomic_store(&recn[r], rn, __ATOMIC_RELAXED,
                               __HIP_MEMORY_SCOPE_AGENT);
          // clear the NEXT epoch's flag slots for chunks cs+1..127
          unsigned* ns = flags + (((r << 1) | ((seq + 1) & 1)) << 10);
          for (int c = ((cs + 1) << 3) + lane; c < (128 << 3); c += 64) ns[c] = 0u;
          __threadfence();
          if (lane == 0)
            __hip_atomic_store(&done[r], (unsigned)(seq + 1),
                               __ATOMIC_RELEASE, __HIP_MEMORY_SCOPE_AGENT);
        }

        while (atload(&done[r]) < (unsigned)(seq + 1))
          __builtin_amdgcn_s_sleep(2);
        __threadfence();
        state.x = sbufB[sb + 0]; state.y = sbufB[sb + 1];
        recc.x  = rbufB[sb + 0]; recc.y  = rbufB[sb + 1];
        sA = sB = sC = sD = state; rA = rB = rC = rD = recc;
        seq += 1;
        jdone = cs;
        i = cs;                 // ++i -> resume at cs+1
        continue;               // skip commit shift
      }
      jdone = j;
    }

    // commit: rotate snapshots, advance state
    sA = sB; sB = sC; sC = sD; sD = state;
    rA = rB; rB = rC; rC = rD; rD = recc;
    state = newstate; recc = newrec;
  }

  // flush spikes belonging to my t-range (after all my zero stores: same-wave
  // program order guarantees zero-then-spike for any shared address)
  unsigned n = atload(&recn[r]);
  __threadfence();
  if (n > 256u) n = 256u;
  for (unsigned e = lane; e < n; e += 64) {
    unsigned long long rc = recl[r * 256 + e];
    unsigned off = (unsigned)(rc >> 32);
    unsigned t = off >> 10;
    if (t / 125u == (unsigned)s)
      outrow[off] = __uint_as_float((unsigned)rc);
  }
}

extern "C" void kernel_launch(void* const* d_in, const int* in_sizes, int n_in,
                              void* d_out, int out_size, void* d_ws, size_t ws_size,
                              hipStream_t stream) {
  const float* x  = (const float*)d_in[0]; // [B,T,N] input_current
  const float* w  = (const float*)d_in[1]; // [N,N] w_rec (row-major [out,in])
  const float* br = (const float*)d_in[2]; // [N] b_rec
  float* out = (float*)d_out;              // [B,T,N] spikes

  // ws layout (bytes):
  //   flags u32[32][2][128][8]     @ 0       (262144)
  //   ready u32[32]                @ 262144  (128)
  //   done  u32[32]                @ 262272  (128)
  //   recn  u32[32]                @ 262400  (128)
  //   recl  u64[32][256]           @ 262528  (65536)
  //   sbufA f32[32][1024]          @ 328064  (131072)
  //   rbufA f32[32][1024]          @ 459136  (131072)
  //   sbufB f32[32][1024]          @ 590208  (131072)
  //   rbufB f32[32][1024]          @ 721280  (131072)  -> total 852352
  char* base = (char*)d_ws;
  unsigned* flags = (unsigned*)(base);
  unsigned* ready = (unsigned*)(base + 262144);
  unsigned* done  = (unsigned*)(base + 262272);
  unsigned* recn  = (unsigned*)(base + 262400);
  unsigned long long* recl = (unsigned long long*)(base + 262528);
  float* sbufA = (float*)(base + 328064);
  float* rbufA = (float*)(base + 459136);
  float* sbufB = (float*)(base + 590208);
  float* rbufB = (float*)(base + 721280);

  init_ctrl<<<64, 256, 0, stream>>>(flags, (262144 + 384) / 4);
  lif_split<<<ROWS_ * SLICES_, TPB_, 0, stream>>>(
      x, w, br, out, flags, ready, done, recn, recl,
      sbufA, rbufA, sbufB, rbufB);
}

// Round 11
// 523.376 us; speedup vs baseline: 1.0396x; 1.0262x over previous
//
#include <hip/hip_runtime.h>
#include <cstdint>
#include <cstddef>

// LIF recurrent SNN, sinabs ThresholdSubtract.
// Round-11: R10's 8-blocks-per-row split (only fix for the measured
//   ~10B/cy/CU delivery wall) x R8's producer/consumer wave split (only
//   mechanism where x-loads never sit on the compute wave's critical path:
//   R9/R10's single wave re-exposed 8 serialized ~700cy latencies/chunk =
//   7100cy/chunk measured).
//   Block = 128 thr: wave0 = consumer (2 neurons/lane, reads depth-8 LDS
//   ring, lgkm-precise), wave1 = producer (4x global_load_lds 16B/lane per
//   chunk, vmcnt(4) drains the chunk issued one iteration earlier -> free).
//   Consensus flags: write-once per (epoch,chunk,slice) relaxed stores; BOTH
//   waves independently verdict from 2-iteration register-prefetched flag
//   reads (~1600cy hiding vs ~300cy latency; spin-reload fallback). Identical
//   verdicts => identical control flow => barrier counts always match.
//   Repair path carried verbatim from R9/R10 (validated bit-exact twice).
#define ROWS_   32
#define SLICES_ 8
#define T_      1000
#define N_      1024
#define NCH_    125          // chunks of 8 steps
#define TPB_    128          // wave0 consumer, wave1 producer
#define W_      4            // confirmation slack (chunks)

typedef float v2f __attribute__((ext_vector_type(2)));
typedef float v4f __attribute__((ext_vector_type(4)));

__device__ __forceinline__ unsigned atload(unsigned* p) {
  return __hip_atomic_load(p, __ATOMIC_RELAXED, __HIP_MEMORY_SCOPE_AGENT);
}
__device__ __forceinline__ unsigned long long atload64(const unsigned long long* p) {
  return __hip_atomic_load(p, __ATOMIC_RELAXED, __HIP_MEMORY_SCOPE_AGENT);
}
__device__ __forceinline__ void atstore(unsigned* p, unsigned v) {
  __hip_atomic_store(p, v, __ATOMIC_RELAXED, __HIP_MEMORY_SCOPE_AGENT);
}

// lgkm-only barrier: producer DMAs / consumer NT stores stay in flight.
__device__ __forceinline__ void barrier_lds() {
  __asm__ volatile("s_waitcnt lgkmcnt(0)\n\ts_barrier" ::: "memory");
}
#define VMWAIT(N) __asm__ volatile("s_waitcnt vmcnt(" #N ")" ::: "memory")

typedef const __attribute__((address_space(1))) void* gas_ptr;
typedef __attribute__((address_space(3))) void*       las_ptr;

__device__ __forceinline__ v4f act4(v4f s) {
  v4f a;
  a.x = (s.x > 0.f) ? floorf(s.x) : 0.f;
  a.y = (s.y > 0.f) ? floorf(s.y) : 0.f;
  a.z = (s.z > 0.f) ? floorf(s.z) : 0.f;
  a.w = (s.w > 0.f) ? floorf(s.w) : 0.f;
  return a;
}
__device__ __forceinline__ unsigned msk4(v4f a, int sh) {
  return ((a.x != 0.f ? 1u : 0u) | (a.y != 0.f ? 2u : 0u) |
          (a.z != 0.f ? 4u : 0u) | (a.w != 0.f ? 8u : 0u)) << sh;
}

__global__ void init_ctrl(unsigned* p, int nwords) {
  int i = blockIdx.x * blockDim.x + threadIdx.x;
  int stride = gridDim.x * blockDim.x;
  for (; i < nwords; i += stride) p[i] = 0u;
}

__global__ __launch_bounds__(TPB_, 1)
void lif_split(const float* __restrict__ x, const float* __restrict__ w,
               const float* __restrict__ brec_g, float* __restrict__ out,
               unsigned* flags, unsigned* ready, unsigned* done,
               unsigned* recn, unsigned long long* recl,
               float* sbufA, float* rbufA, float* sbufB, float* rbufB)
{
  const int g    = blockIdx.x;
  const int r    = g & 31;        // row; all 8 slices of a row share XCD r%8
  const int s    = g >> 5;        // slice 0..7 (slice 0 = row leader)
  const int tid  = threadIdx.x;
  const int lane = tid & 63;
  const int wvid = tid >> 6;      // 0 = consumer, 1 = producer

  __shared__ float xring[8][8][128];   // depth-8 chunk ring (16KB)
  __shared__ float lacts[N_];          // leader replay act broadcast

  const float* xb = x + (size_t)r * (T_ * N_);

  // verdict: all 8 slices posted chunk j (bit0), any spike (bit1)?
  // pf regs give 2-iteration prefetch; spin-reload is the rare fallback.
#define VERDICT(spikevar, jv)                                                \
  do {                                                                       \
    const unsigned long long* fp = (const unsigned long long*)               \
        (flags + (((r << 1) | (seq & 1)) << 10) + ((jv) << 3));              \
    unsigned long long f0, f1, f2, f3;                                       \
    if (pfj == (jv)) { f0 = p0; f1 = p1; f2 = p2; f3 = p3; }                 \
    else { f0 = f1 = f2 = f3 = 0; }                                          \
    for (;;) {                                                               \
      unsigned long long pp = f0 & f1 & f2 & f3;                             \
      if ((pp & 1ull) && (pp & (1ull << 32))) break;                         \
      __builtin_amdgcn_s_sleep(2);                                           \
      f0 = atload64(fp); f1 = atload64(fp + 1);                              \
      f2 = atload64(fp + 2); f3 = atload64(fp + 3);                          \
    }                                                                        \
    spikevar = ((f0 | f1 | f2 | f3) & 0x0000000200000002ull) ? 1 : 0;        \
  } while (0)

#define PREFETCH(iv)                                                         \
  do {                                                                       \
    int _jn = (iv) - W_ + 2;                                                 \
    if (_jn >= 0 && _jn < NCH_) {                                            \
      const unsigned long long* _fq = (const unsigned long long*)            \
          (flags + (((r << 1) | (seq & 1)) << 10) + (_jn << 3));             \
      p0 = atload64(_fq); p1 = atload64(_fq + 1);                            \
      p2 = atload64(_fq + 2); p3 = atload64(_fq + 3);                        \
      pfj = _jn;                                                             \
    }                                                                        \
  } while (0)

  if (wvid == 1) {
    // ------------------------- producer wave ------------------------------
    const int rowoff = lane >> 5;        // 0 or 1: which of 2 rows per DMA
    const int coloff = (lane & 31) << 2; // float offset within the row slice
    auto issue = [&](int cc) {
      const int slot = cc & 7;
#pragma unroll
      for (int q = 0; q < 4; ++q) {
        const float* gsrc =
            xb + (size_t)(cc * 8 + 2 * q + rowoff) * N_ + s * 128 + coloff;
        __builtin_amdgcn_global_load_lds((gas_ptr)gsrc,
                                         (las_ptr)&xring[slot][2 * q][0],
                                         16, 0, 0);
      }
    };
    issue(0); issue(1);
    VMWAIT(4);                   // chunk 0 landed (chunk 1 in flight)
    barrier_lds();

    int jdone = -1, seq = 0, pfj = -100;
    unsigned long long p0 = 0, p1 = 0, p2 = 0, p3 = 0;
#pragma unroll 1
    for (int i = 0; i < NCH_ + W_; ++i) {
      const int j = i - W_;
      const bool needc = (j > jdone) && (j >= 0);
      if (i + 2 < NCH_) { issue(i + 2); VMWAIT(4); }  // drain chunk i+1
      else             { VMWAIT(0); }
      int spike = 0;
      if (needc) VERDICT(spike, j);
      if (!spike) PREFETCH(i);
      barrier_lds();
      if (spike) { seq++; jdone = j; pfj = -100; i = j; continue; }
      if (needc) jdone = j;
    }
    return;
  }

  // --------------------------- consumer wave ------------------------------
  float* outrow = out + (size_t)r * (T_ * N_);
  v4f*   zbase  = (v4f*)(outrow + (size_t)s * 125 * N_);  // my t-range
  const v2f brecv = *(const v2f*)(brec_g + s * 128 + lane * 2);

  v2f state = (v2f)(0.f), recc = (v2f)(0.f);   // chunk-0 rec = 0 (NOT brec)
  v2f sA = state, sB = state, sC = state, sD = state;  // starts of i-4..i-1
  v2f rA = recc,  rB = recc,  rC = recc,  rD = recc;
  int jdone = -1, seq = 0, pfj = -100;
  unsigned long long p0 = 0, p1 = 0, p2 = 0, p3 = 0;
  const v4f z4 = (v4f)(0.f);

  barrier_lds();               // match producer prologue barrier

#pragma unroll 1
  for (int i = 0; i < NCH_ + W_; ++i) {
    const int j = i - W_;
    const bool needc = (j > jdone) && (j >= 0);

    v2f newstate = state, newrec = recc;
    if (i < NCH_) {
      // interleaved zeroing: 4KB of my out t-range per iteration
      v4f* zp = zbase + (size_t)i * 256;
      __builtin_nontemporal_store(z4, zp +   0 + lane);
      __builtin_nontemporal_store(z4, zp +  64 + lane);
      __builtin_nontemporal_store(z4, zp + 128 + lane);
      __builtin_nontemporal_store(z4, zp + 192 + lane);

      // speculative no-spike pass on chunk i, x from the LDS ring
      const float* xs = &xring[i & 7][0][0];
      v2f x0 = *(const v2f*)(xs + 0 * 128 + lane * 2);
      v2f x1 = *(const v2f*)(xs + 1 * 128 + lane * 2);
      v2f x2 = *(const v2f*)(xs + 2 * 128 + lane * 2);
      v2f x3 = *(const v2f*)(xs + 3 * 128 + lane * 2);
      v2f x4 = *(const v2f*)(xs + 4 * 128 + lane * 2);
      v2f x5 = *(const v2f*)(xs + 5 * 128 + lane * 2);
      v2f x6 = *(const v2f*)(xs + 6 * 128 + lane * 2);
      v2f x7 = *(const v2f*)(xs + 7 * 128 + lane * 2);
      v2f st = state, rr = recc, cm = state;
#define SSTEP(xk)                                                            \
      do {                                                                   \
        cm.x = fmaxf(cm.x, st.x); cm.y = fmaxf(cm.y, st.y);                  \
        v2f _t = (xk) + rr;                                                  \
        st = st * 0.9f + 0.1f * _t;                                          \
        rr = brecv;                                                          \
      } while (0)
      SSTEP(x0); SSTEP(x1); SSTEP(x2); SSTEP(x3);
      SSTEP(x4); SSTEP(x5); SSTEP(x6); SSTEP(x7);
#undef SSTEP
      int any = (fmaxf(cm.x, cm.y) >= 1.0f);
      unsigned long long bal = __ballot(any);
      if (lane == 0)
        atstore(flags + (((r << 1) | (seq & 1)) << 10) + (i << 3) + s,
                bal ? 3u : 1u);
      newstate = st; newrec = brecv;
    }

    int spike = 0;
    if (needc) VERDICT(spike, j);
    if (!spike) PREFETCH(i);

    barrier_lds();

    if (spike) {
      // -------- rollback & exact repair of chunk j (R9/R10-validated) -----
      const int cs = j;
      const int sb = r * 1024 + s * 128 + lane * 2;
      sbufA[sb + 0] = sA.x; sbufA[sb + 1] = sA.y;   // start(cs) state
      rbufA[sb + 0] = rA.x; rbufA[sb + 1] = rA.y;   // start(cs) rec
      __threadfence();
      if (lane == 0) atomicAdd(&ready[r], 1u);

      if (s == 0) {
        const unsigned tgt = 8u * (unsigned)(seq + 1);
        while (atload(&ready[r]) < tgt) __builtin_amdgcn_s_sleep(2);
        __threadfence();
        const int nl = lane * 16;             // my 16 neurons
        v4f s0 = *(v4f*)(sbufA + r * 1024 + nl + 0);
        v4f s1 = *(v4f*)(sbufA + r * 1024 + nl + 4);
        v4f s2 = *(v4f*)(sbufA + r * 1024 + nl + 8);
        v4f s3 = *(v4f*)(sbufA + r * 1024 + nl + 12);
        v4f r0 = *(v4f*)(rbufA + r * 1024 + nl + 0);
        v4f r1 = *(v4f*)(rbufA + r * 1024 + nl + 4);
        v4f r2 = *(v4f*)(rbufA + r * 1024 + nl + 8);
        v4f r3 = *(v4f*)(rbufA + r * 1024 + nl + 12);
        const v4f bb0 = *(const v4f*)(brec_g + nl + 0);
        const v4f bb1 = *(const v4f*)(brec_g + nl + 4);
        const v4f bb2 = *(const v4f*)(brec_g + nl + 8);
        const v4f bb3 = *(const v4f*)(brec_g + nl + 12);
        unsigned rn = atload(&recn[r]);
        const float* xc = xb + (size_t)cs * 8 * N_ + nl;
#pragma unroll 1
        for (int k = 0; k < 8; ++k) {
          v4f xa = *(const v4f*)(xc + k * N_ + 0);
          v4f xbv = *(const v4f*)(xc + k * N_ + 4);
          v4f xcv = *(const v4f*)(xc + k * N_ + 8);
          v4f xd = *(const v4f*)(xc + k * N_ + 12);
          v4f t0 = xa + r0, t1 = xbv + r1, t2 = xcv + r2, t3 = xd + r3;
          v4f a0 = act4(s0), a1 = act4(s1), a2 = act4(s2), a3 = act4(s3);
          unsigned m16 = msk4(a0, 0) | msk4(a1, 4) | msk4(a2, 8) | msk4(a3, 12);
          if (m16) {
            *(v4f*)(lacts + nl + 0)  = a0; *(v4f*)(lacts + nl + 4)  = a1;
            *(v4f*)(lacts + nl + 8)  = a2; *(v4f*)(lacts + nl + 12) = a3;
          }
          unsigned long long spk = __ballot(m16 != 0);
          s0 = (s0 - a0) * 0.9f + 0.1f * t0;
          s1 = (s1 - a1) * 0.9f + 0.1f * t1;
          s2 = (s2 - a2) * 0.9f + 0.1f * t2;
          s3 = (s3 - a3) * 0.9f + 0.1f * t3;
          r0 = bb0; r1 = bb1; r2 = bb2; r3 = bb3;
          while (spk) {                       // rank-1 per spiking neuron
            int L = __builtin_ctzll(spk); spk &= spk - 1;
            unsigned m = (unsigned)__shfl((int)m16, L);
            while (m) {
              int bp = __builtin_ctz(m); m &= m - 1;
              int jj = (L << 4) + bp;
              float a = lacts[jj];
              const float* wc = w + jj;
              r0.x += a * wc[(size_t)(nl + 0) * N_];
              r0.y += a * wc[(size_t)(nl + 1) * N_];
              r0.z += a * wc[(size_t)(nl + 2) * N_];
              r0.w += a * wc[(size_t)(nl + 3) * N_];
              r1.x += a * wc[(size_t)(nl + 4) * N_];
              r1.y += a * wc[(size_t)(nl + 5) * N_];
              r1.z += a * wc[(size_t)(nl + 6) * N_];
              r1.w += a * wc[(size_t)(nl + 7) * N_];
              r2.x += a * wc[(size_t)(nl + 8) * N_];
              r2.y += a * wc[(size_t)(nl + 9) * N_];
              r2.z += a * wc[(size_t)(nl + 10) * N_];
              r2.w += a * wc[(size_t)(nl + 11) * N_];
              r3.x += a * wc[(size_t)(nl + 12) * N_];
              r3.y += a * wc[(size_t)(nl + 13) * N_];
              r3.z += a * wc[(size_t)(nl + 14) * N_];
              r3.w += a * wc[(size_t)(nl + 15) * N_];
              if (lane == 0) {                // record spike (t*N + n, val)
                unsigned off = (unsigned)((cs * 8 + k) * N_ + jj);
                recl[r * 256 + (rn & 255u)] =
                    ((unsigned long long)off << 32) |
                    (unsigned long long)__float_as_uint(a);
                rn++;
              }
            }
          }
        }
        *(v4f*)(sbufB + r * 1024 + nl + 0)  = s0;
        *(v4f*)(sbufB + r * 1024 + nl + 4)  = s1;
        *(v4f*)(sbufB + r * 1024 + nl + 8)  = s2;
        *(v4f*)(sbufB + r * 1024 + nl + 12) = s3;
        *(v4f*)(rbufB + r * 1024 + nl + 0)  = r0;
        *(v4f*)(rbufB + r * 1024 + nl + 4)  = r1;
        *(v4f*)(rbufB + r * 1024 + nl + 8)  = r2;
        *(v4f*)(rbufB + r * 1024 + nl + 12) = r3;
        if (lane == 0)
          __hip_atomic_store(&recn[r], rn, __ATOMIC_RELAXED,
                             __HIP_MEMORY_SCOPE_AGENT);
        // clear the NEXT epoch's flag slots for chunks cs+1..127
        unsigned* ns = flags + (((r << 1) | ((seq + 1) & 1)) << 10);
        for (int c = ((cs + 1) << 3) + lane; c < (128 << 3); c += 64) ns[c] = 0u;
        __threadfence();
        if (lane == 0)
          __hip_atomic_store(&done[r], (unsigned)(seq + 1),
                             __ATOMIC_RELEASE, __HIP_MEMORY_SCOPE_AGENT);
      }

      while (atload(&done[r]) < (unsigned)(seq + 1))
        __builtin_amdgcn_s_sleep(2);
      __threadfence();
      state.x = sbufB[sb + 0]; state.y = sbufB[sb + 1];
      recc.x  = rbufB[sb + 0]; recc.y  = rbufB[sb + 1];
      sA = sB = sC = sD = state; rA = rB = rC = rD = recc;
      seq += 1; jdone = cs; pfj = -100;
      i = cs;                 // ++i -> resume at cs+1
      continue;
    }

    if (needc) jdone = j;
    // commit: rotate snapshots, advance state
    sA = sB; sB = sC; sC = sD; sD = state;
    rA = rB; rB = rC; rC = rD; rD = recc;
    state = newstate; recc = newrec;
  }

  // flush spikes belonging to my t-range (after my zero stores: same-wave
  // program order guarantees zero-then-spike for any shared address)
  unsigned n = atload(&recn[r]);
  __threadfence();
  if (n > 256u) n = 256u;
  for (unsigned e = lane; e < n; e += 64) {
    unsigned long long rc = recl[r * 256 + e];
    unsigned off = (unsigned)(rc >> 32);
    unsigned t = off >> 10;
    if (t / 125u == (unsigned)s)
      outrow[off] = __uint_as_float((unsigned)rc);
  }
#undef VERDICT
#undef PREFETCH
}

extern "C" void kernel_launch(void* const* d_in, const int* in_sizes, int n_in,
                              void* d_out, int out_size, void* d_ws, size_t ws_size,
                              hipStream_t stream) {
  const float* x  = (const float*)d_in[0]; // [B,T,N] input_current
  const float* w  = (const float*)d_in[1]; // [N,N] w_rec (row-major [out,in])
  const float* br = (const float*)d_in[2]; // [N] b_rec
  float* out = (float*)d_out;              // [B,T,N] spikes

  // ws layout (bytes): flags u32[32][2][128][8] @0 (262144); ready u32[32]
  // @262144; done u32[32] @262272; recn u32[32] @262400; recl u64[32][256]
  // @262528; sbufA/rbufA/sbufB/rbufB f32[32][1024] @328064.. (+131072 each)
  char* base = (char*)d_ws;
  unsigned* flags = (unsigned*)(base);
  unsigned* ready = (unsigned*)(base + 262144);
  unsigned* done  = (unsigned*)(base + 262272);
  unsigned* recn  = (unsigned*)(base + 262400);
  unsigned long long* recl = (unsigned long long*)(base + 262528);
  float* sbufA = (float*)(base + 328064);
  float* rbufA = (float*)(base + 459136);
  float* sbufB = (float*)(base + 590208);
  float* rbufB = (float*)(base + 721280);

  init_ctrl<<<64, 256, 0, stream>>>(flags, (262144 + 384) / 4);
  lif_split<<<ROWS_ * SLICES_, TPB_, 0, stream>>>(
      x, w, br, out, flags, ready, done, recn, recl,
      sbufA, rbufA, sbufB, rbufB);
}